// Round 19
// baseline (50.536 us; speedup 1.0000x reference)
//
#include <hip/hip_runtime.h>
#include <hip/hip_bf16.h>
#include <math.h>

// Sizes fixed by the reference: B=16, N=2048, F_in=F_out=64.
#define NB 16
#define NN 2048
#define NF 64
#define LOG2E 1.44269504f

// g(t) nearest-neighbor table: t in [T_LO, T_HI], NT bins, value at bin midpoint.
#define NT 4096
#define T_LO (-40.0f)
#define T_HI (10.0f)
#define T_SCALE (NT / (T_HI - T_LO))         // 81.92 bins per unit t
#define Z_BIAS (-T_LO * T_SCALE)             // 3276.8
#define Z_MAX ((float)(NT - 1))

// F/G sampling grid (in t-units): 512 points over [-96, 96), step 0.375.
// gs[p] = g(2*XG_LO + p*DXG), p in [0,1024): composed grid for the F-convolution.
#define MG 512
#define XG_LO (-96.0f)
#define DXG 0.375f
#define INV_DXG (1.0f / DXG)                 // 2.666667
#define U_BIAS (-XG_LO * INV_DXG)            // 256.0
#define U_MAX 510.999f                       // clamp so k+1 <= 511
#define GS_N 1024

typedef __attribute__((ext_vector_type(8))) __bf16 bf16x8;
typedef __attribute__((ext_vector_type(8))) short  short8;
typedef __attribute__((ext_vector_type(4))) float  f32x4;

__device__ __forceinline__ float gexact(float t) {
    float v = t >= 0.f ? t : 0.2f * t;
    float s = 1.f / (1.f + expf(-v));
    return expf(s);
}

__device__ __forceinline__ float tlookup(const float* __restrict__ stab, float z) {
    float zc = __builtin_amdgcn_fmed3f(z, 0.f, Z_MAX);
    return stab[(int)zc];
}

__device__ __forceinline__ float elu(float v) {
    return v > 0.f ? v : (__builtin_amdgcn_exp2f(v * LOG2E) - 1.f);
}

// ---------------- Pass A: Wh via bf16 MFMA, emitted directly as MFMA B-fragments;
// x,y scalars via associativity (h.(W@a1)). Blocks 0..15 build gtab, 16..19 build gs.
__global__ __launch_bounds__(256) void k_prep(const float* __restrict__ h,
                                              const float* __restrict__ W,
                                              const float* __restrict__ a,
                                              uint4* __restrict__ vfrag,
                                              float* __restrict__ ys,
                                              float* __restrict__ xs_u,
                                              float* __restrict__ ys_u,
                                              float* __restrict__ gtab,
                                              float* __restrict__ gs) {
    __shared__ __attribute__((aligned(16))) float  hT[64 * 68];    // padded (+4 f32)
    __shared__ __attribute__((aligned(16))) __bf16 WbT[64 * 72];   // transposed, padded
    __shared__ __attribute__((aligned(16))) __bf16 vT[64 * 74];    // Wh bf16, stride-74
    __shared__ float uv[128];                                      // u[0..64), v[64..128)
    int t  = threadIdx.x;
    int r0 = blockIdx.x * 64;
    int b  = blockIdx.x >> 5;
    const float4* hsrc = (const float4*)(h + r0 * 64);
#pragma unroll
    for (int i = 0; i < 4; i++) {
        int flat = t + i * 256;            // float4 index in 64x16
        int row = flat >> 4, c4 = flat & 15;
        float4 hv = hsrc[flat];
        float* dst = &hT[row * 68 + c4 * 4];
        dst[0] = hv.x; dst[1] = hv.y; dst[2] = hv.z; dst[3] = hv.w;
    }
#pragma unroll
    for (int i = 0; i < 4; i++) {
        int flat = t + i * 256;
        int k = flat >> 4, c4 = flat & 15;
        float4 wv = ((const float4*)W)[flat];
        WbT[(c4 * 4 + 0) * 72 + k] = (__bf16)wv.x;
        WbT[(c4 * 4 + 1) * 72 + k] = (__bf16)wv.y;
        WbT[(c4 * 4 + 2) * 72 + k] = (__bf16)wv.z;
        WbT[(c4 * 4 + 3) * 72 + k] = (__bf16)wv.w;
    }
    // u = W@a1, v = W@a2 (exact f32 from global W)
    if (t < 64) {
        float s = 0.f;
#pragma unroll 8
        for (int f = 0; f < 64; f++) s = fmaf(W[t * 64 + f], a[f], s);
        uv[t] = s;
    } else if (t < 128) {
        int k = t - 64;
        float s = 0.f;
#pragma unroll 8
        for (int f = 0; f < 64; f++) s = fmaf(W[k * 64 + f], a[64 + f], s);
        uv[64 + k] = s;
    }
    __syncthreads();
    // x,y scalars: 4 threads per row, shfl reduce
    {
        int row = t >> 2, q = t & 3;
        const float* hp = &hT[row * 68 + q * 16];
        const float* up = &uv[q * 16];
        const float* vp = &uv[64 + q * 16];
        float sx = 0.f, sy = 0.f;
#pragma unroll
        for (int k2 = 0; k2 < 16; k2++) {
            float hv = hp[k2];
            sx = fmaf(hv, up[k2], sx);
            sy = fmaf(hv, vp[k2], sy);
        }
        sx += __shfl_xor(sx, 1); sx += __shfl_xor(sx, 2);
        sy += __shfl_xor(sy, 1); sy += __shfl_xor(sy, 2);
        if (q == 0) {
            int r = r0 + row;
            ys[r]   = T_SCALE * sy;
            xs_u[r] = __builtin_amdgcn_fmed3f(sx * INV_DXG + U_BIAS, 0.f, U_MAX);
            ys_u[r] = __builtin_amdgcn_fmed3f(sy * INV_DXG + U_BIAS, 0.f, U_MAX);
        }
    }
    // Wh via MFMA: wave w -> 16-row tile; K=64 (2 k-steps); 4 n-tiles
    int w = t >> 6, lane = t & 63;
    int il = lane & 15, kg = lane >> 4;
    f32x4 acc0 = {0.f,0.f,0.f,0.f}, acc1 = {0.f,0.f,0.f,0.f};
    f32x4 acc2 = {0.f,0.f,0.f,0.f}, acc3 = {0.f,0.f,0.f,0.f};
#pragma unroll
    for (int ks = 0; ks < 2; ks++) {
        const float* ap = &hT[(w * 16 + il) * 68 + ks * 32 + kg * 8];
        bf16x8 af;
#pragma unroll
        for (int e = 0; e < 8; e++) af[e] = (__bf16)ap[e];
        bf16x8 b0 = *(const bf16x8*)&WbT[(0 * 16 + il) * 72 + ks * 32 + kg * 8];
        bf16x8 b1 = *(const bf16x8*)&WbT[(1 * 16 + il) * 72 + ks * 32 + kg * 8];
        bf16x8 b2 = *(const bf16x8*)&WbT[(2 * 16 + il) * 72 + ks * 32 + kg * 8];
        bf16x8 b3 = *(const bf16x8*)&WbT[(3 * 16 + il) * 72 + ks * 32 + kg * 8];
        acc0 = __builtin_amdgcn_mfma_f32_16x16x32_bf16(af, b0, acc0, 0, 0, 0);
        acc1 = __builtin_amdgcn_mfma_f32_16x16x32_bf16(af, b1, acc1, 0, 0, 0);
        acc2 = __builtin_amdgcn_mfma_f32_16x16x32_bf16(af, b2, acc2, 0, 0, 0);
        acc3 = __builtin_amdgcn_mfma_f32_16x16x32_bf16(af, b3, acc3, 0, 0, 0);
    }
    // C-layout -> LDS bf16 (col = il + nt*16, row = w*16 + kg*4 + r)
#pragma unroll
    for (int r = 0; r < 4; r++) {
        __bf16* vrow = &vT[(w * 16 + kg * 4 + r) * 74 + il];
        vrow[0]  = (__bf16)acc0[r];
        vrow[16] = (__bf16)acc1[r];
        vrow[32] = (__bf16)acc2[r];
        vrow[48] = (__bf16)acc3[r];
    }
    __syncthreads();
    // Emit B-fragments: slot (ksl, nt, lane'): elem e = Wh[ksl*32+(lane'>>4)*8+e][nt*16+(lane'&15)]
#pragma unroll
    for (int s = 0; s < 2; s++) {
        int oi    = t + s * 256;
        int lane2 = oi & 63;
        int nt2   = (oi >> 6) & 3;
        int ksl   = oi >> 8;
        int rbase = ksl * 32 + ((lane2 >> 4) << 3);
        int col   = nt2 * 16 + (lane2 & 15);
        short8 o;
#pragma unroll
        for (int e = 0; e < 8; e++)
            o[e] = __builtin_bit_cast(short, vT[(rbase + e) * 74 + col]);
        int ks_g = ((blockIdx.x & 31) << 1) | ksl;
        vfrag[((b * 64 + ks_g) * 4 + nt2) * 64 + lane2] = __builtin_bit_cast(uint4, o);
    }
    if (blockIdx.x < 16) {
        int i = blockIdx.x * 256 + t;
        gtab[i] = gexact(T_LO + ((float)i + 0.5f) / T_SCALE);
    } else if (blockIdx.x < 20) {
        int i = (blockIdx.x - 16) * 256 + t;
        gs[i] = gexact(2.f * XG_LO + (float)i * DXG);
    }
}

// ---------------- Pass B: G[b][m][f] = sum_j (g(xm*+y_j)*dinv_j) * Wh[j][f]
// (MFMA, K=2048). Prologue computes F in-block via the histogram convolution
// F[m] = sum_k Hx[k]*gs[k+m]  (R13-validated), then dinv = 1/lerp(F, y_j).
// Conv scratch {gsb,hxb,Fb} ALIASES red (used only after the main loop).
// A-frag (16x32): row = lane&15, k = (lane>>4)*8 + e
// C/D frag:       col = lane&15, row = (lane>>4)*4 + reg   [verified layout]
__global__ __launch_bounds__(512) void k_gbuild(const float* __restrict__ ys,
                                                const float* __restrict__ ys_u,
                                                const float* __restrict__ xs_u,
                                                const float* __restrict__ gtab,
                                                const float* __restrict__ gs,
                                                const uint4* __restrict__ vfrag,
                                                float* __restrict__ G) {
    __shared__ float stab[NT];       // 16 KB
    __shared__ float dinvb[NN];      // 8 KB
    __shared__ float red[7][16][65]; // 29 KB; prologue aliases {gsb,hxb,Fb}
    float* gsb = &red[0][0][0];          // 1024 f
    float* hxb = gsb + GS_N;             // 512 f
    float* Fb  = hxb + MG;               // 512 f
    int t = threadIdx.x;
    int b  = blockIdx.x >> 5;
    int ib = blockIdx.x & 31;
    {
        const float4* src = (const float4*)gtab;
        float4*       dst = (float4*)stab;
#pragma unroll
        for (int k = 0; k < NT / 4 / 512; k++) dst[t + k * 512] = src[t + k * 512];
    }
    if (t < 256) ((float4*)gsb)[t] = ((const float4*)gs)[t];
    hxb[t] = 0.f;                      // t in [0,512) == MG
    __syncthreads();
    // x-histogram (linear split): 2048 rows, 4 per thread
#pragma unroll
    for (int i = 0; i < 4; i++) {
        float xu = xs_u[b * NN + i * 512 + t];
        int   k  = (int)xu;
        float fr = xu - (float)k;
        atomicAdd(&hxb[k],     1.f - fr);
        atomicAdd(&hxb[k + 1], fr);
    }
    __syncthreads();
    // F-conv: thread t owns m = t (512 threads). hx[k] broadcasts; gsb[k+m] stride-1.
    {
        float acc = 0.f;
        for (int k = 0; k < MG; k++) acc = fmaf(hxb[k], gsb[k + t], acc);
        Fb[t] = acc;
    }
    __syncthreads();
    // dinv: 2048 lerp(F)+rcp, 4 per thread
#pragma unroll
    for (int i = 0; i < 4; i++) {
        int j = t + i * 512;
        float u  = ys_u[b * NN + j];
        int   k  = (int)u;
        float fr = u - (float)k;
        float d  = fmaf(Fb[k + 1] - Fb[k], fr, Fb[k]);
        dinvb[j] = __builtin_amdgcn_rcpf(d);
    }
    int kz = t >> 6, lane = t & 63;
    int il = lane & 15, kg = lane >> 4;
    int mbase = ib * 16;

    float xgb = (XG_LO + (float)(mbase + il) * DXG) * T_SCALE + Z_BIAS;
    const float* ysb = ys + b * NN;
    const uint4* vfb = vfrag + b * 16384 + lane;
    __syncthreads();

    f32x4 acc0 = {0.f,0.f,0.f,0.f}, acc1 = {0.f,0.f,0.f,0.f};
    f32x4 acc2 = {0.f,0.f,0.f,0.f}, acc3 = {0.f,0.f,0.f,0.f};

    for (int ks = kz * 8; ks < kz * 8 + 8; ks++) {
        const float* yp = ysb + ks * 32 + kg * 8;
        const float* dp = &dinvb[ks * 32 + kg * 8];
        float4 ya = *reinterpret_cast<const float4*>(yp);
        float4 yb = *reinterpret_cast<const float4*>(yp + 4);
        float wv[8];
        wv[0] = tlookup(stab, xgb + ya.x);
        wv[1] = tlookup(stab, xgb + ya.y);
        wv[2] = tlookup(stab, xgb + ya.z);
        wv[3] = tlookup(stab, xgb + ya.w);
        wv[4] = tlookup(stab, xgb + yb.x);
        wv[5] = tlookup(stab, xgb + yb.y);
        wv[6] = tlookup(stab, xgb + yb.z);
        wv[7] = tlookup(stab, xgb + yb.w);
        bf16x8 af;
#pragma unroll
        for (int e = 0; e < 8; e++) af[e] = (__bf16)(wv[e] * dp[e]);

        const uint4* vp = vfb + ks * 256;
        bf16x8 b0 = __builtin_bit_cast(bf16x8, vp[0]);
        bf16x8 b1 = __builtin_bit_cast(bf16x8, vp[64]);
        bf16x8 b2 = __builtin_bit_cast(bf16x8, vp[128]);
        bf16x8 b3 = __builtin_bit_cast(bf16x8, vp[192]);

        acc0 = __builtin_amdgcn_mfma_f32_16x16x32_bf16(af, b0, acc0, 0, 0, 0);
        acc1 = __builtin_amdgcn_mfma_f32_16x16x32_bf16(af, b1, acc1, 0, 0, 0);
        acc2 = __builtin_amdgcn_mfma_f32_16x16x32_bf16(af, b2, acc2, 0, 0, 0);
        acc3 = __builtin_amdgcn_mfma_f32_16x16x32_bf16(af, b3, acc3, 0, 0, 0);
    }

    if (kz > 0) {
#pragma unroll
        for (int r = 0; r < 4; r++) {
            float* rp = &red[kz - 1][kg * 4 + r][il];
            rp[0]  = acc0[r];
            rp[16] = acc1[r];
            rp[32] = acc2[r];
            rp[48] = acc3[r];
        }
    }
    __syncthreads();
    if (kz == 0) {
        int gbase = (b * MG + mbase + kg * 4) * 64 + il;
#pragma unroll
        for (int r = 0; r < 4; r++) {
            float s0 = acc0[r], s1 = acc1[r], s2 = acc2[r], s3 = acc3[r];
#pragma unroll
            for (int p = 0; p < 7; p++) {
                const float* rp = &red[p][kg * 4 + r][il];
                s0 += rp[0]; s1 += rp[16]; s2 += rp[32]; s3 += rp[48];
            }
            float* grow = G + gbase + r * 64;
            grow[0] = s0; grow[16] = s1; grow[32] = s2; grow[48] = s3;
        }
    }
}

// ---------------- Pass C: out[i][f] = ELU( lerp_x(G_b)(x_i)[f] )  [R16 verbatim]
__global__ __launch_bounds__(256) void k_apply(const float* __restrict__ xs_u,
                                               const float* __restrict__ G,
                                               float* __restrict__ out) {
    int w = threadIdx.x >> 6, f = threadIdx.x & 63;
    int r = blockIdx.x * 4 + w;
    int b = r >> 11;
    float u  = xs_u[r];
    int   k  = (int)u;
    float fr = u - (float)k;
    const float* Gb = G + (b * MG + k) * 64;
    float g0 = Gb[f];
    float g1 = Gb[64 + f];
    out[r * 64 + f] = elu(fmaf(g1 - g0, fr, g0));
}

extern "C" void kernel_launch(void* const* d_in, const int* in_sizes, int n_in,
                              void* d_out, int out_size, void* d_ws, size_t ws_size,
                              hipStream_t stream) {
    const float* h = (const float*)d_in[0];
    const float* W = (const float*)d_in[1];
    const float* a = (const float*)d_in[2];
    float* out = (float*)d_out;

    // workspace layout (floats), ~7 MB total
    float*  ys    = (float*)d_ws;                  // B*N (z-scaled y)
    float*  xs_u  = ys + NB * NN;                  // B*N (grid coords of x)
    float*  ys_u  = xs_u + NB * NN;                // B*N (grid coords of y)
    float*  G     = ys_u + NB * NN;                // B*MG*64 = 524,288 f
    uint4*  vfrag = (uint4*)(G + NB * MG * NF);    // B*N*64 bf16 = 4 MB
    float*  gtab  = (float*)(vfrag + NB * NN * NF / 8);  // 4096 f32
    float*  gs    = gtab + NT;                     // 1024 f32

    k_prep<<<dim3(NB * NN / 64), dim3(256), 0, stream>>>(h, W, a, vfrag, ys, xs_u, ys_u, gtab, gs);
    k_gbuild<<<dim3(NB * (MG / 16)), dim3(512), 0, stream>>>(ys, ys_u, xs_u, gtab, gs, vfrag, G);
    k_apply<<<dim3(NB * NN / 4), dim3(256), 0, stream>>>(xs_u, G, out);
}

// Round 20
// 40.823 us; speedup vs baseline: 1.2379x; 1.2379x over previous
//
#include <hip/hip_runtime.h>
#include <hip/hip_bf16.h>
#include <math.h>

// Sizes fixed by the reference: B=16, N=2048, F_in=F_out=64.
#define NB 16
#define NN 2048
#define NF 64
#define LOG2E 1.44269504f

// g(t) nearest-neighbor table: t in [T_LO, T_HI], NT bins, value at bin midpoint.
#define NT 4096
#define T_LO (-40.0f)
#define T_HI (10.0f)
#define T_SCALE (NT / (T_HI - T_LO))         // 81.92 bins per unit t
#define Z_BIAS (-T_LO * T_SCALE)             // 3276.8
#define Z_MAX ((float)(NT - 1))

// F/G sampling grid (in t-units): 512 points over [-96, 96), step 0.375.
// gs[p] = g(2*XG_LO + p*DXG), p in [0,1024): composed grid for the F-convolution.
#define MG 512
#define XG_LO (-96.0f)
#define DXG 0.375f
#define INV_DXG (1.0f / DXG)                 // 2.666667
#define U_BIAS (-XG_LO * INV_DXG)            // 256.0
#define U_MAX 510.999f                       // clamp so k+1 <= 511
#define GS_N 1024

typedef __attribute__((ext_vector_type(8))) __bf16 bf16x8;
typedef __attribute__((ext_vector_type(8))) short  short8;
typedef __attribute__((ext_vector_type(4))) float  f32x4;

__device__ __forceinline__ float gexact(float t) {
    float v = t >= 0.f ? t : 0.2f * t;
    float s = 1.f / (1.f + expf(-v));
    return expf(s);
}

__device__ __forceinline__ float tlookup(const float* __restrict__ stab, float z) {
    float zc = __builtin_amdgcn_fmed3f(z, 0.f, Z_MAX);
    return stab[(int)zc];
}

__device__ __forceinline__ float elu(float v) {
    return v > 0.f ? v : (__builtin_amdgcn_exp2f(v * LOG2E) - 1.f);
}

// ---------------- Pass A: Wh via bf16 MFMA, emitted directly as MFMA B-fragments;
// x,y scalars via associativity (h.(W@a1)). Blocks 0..15 build gtab, 16..19 build gs.
__global__ __launch_bounds__(256) void k_prep(const float* __restrict__ h,
                                              const float* __restrict__ W,
                                              const float* __restrict__ a,
                                              uint4* __restrict__ vfrag,
                                              float* __restrict__ ys,
                                              float* __restrict__ xs_u,
                                              float* __restrict__ ys_u,
                                              float* __restrict__ gtab,
                                              float* __restrict__ gs) {
    __shared__ __attribute__((aligned(16))) float  hT[64 * 68];    // padded (+4 f32)
    __shared__ __attribute__((aligned(16))) __bf16 WbT[64 * 72];   // transposed, padded
    __shared__ __attribute__((aligned(16))) __bf16 vT[64 * 74];    // Wh bf16, stride-74
    __shared__ float uv[128];                                      // u[0..64), v[64..128)
    int t  = threadIdx.x;
    int r0 = blockIdx.x * 64;
    int b  = blockIdx.x >> 5;
    const float4* hsrc = (const float4*)(h + r0 * 64);
#pragma unroll
    for (int i = 0; i < 4; i++) {
        int flat = t + i * 256;            // float4 index in 64x16
        int row = flat >> 4, c4 = flat & 15;
        float4 hv = hsrc[flat];
        float* dst = &hT[row * 68 + c4 * 4];
        dst[0] = hv.x; dst[1] = hv.y; dst[2] = hv.z; dst[3] = hv.w;
    }
#pragma unroll
    for (int i = 0; i < 4; i++) {
        int flat = t + i * 256;
        int k = flat >> 4, c4 = flat & 15;
        float4 wv = ((const float4*)W)[flat];
        WbT[(c4 * 4 + 0) * 72 + k] = (__bf16)wv.x;
        WbT[(c4 * 4 + 1) * 72 + k] = (__bf16)wv.y;
        WbT[(c4 * 4 + 2) * 72 + k] = (__bf16)wv.z;
        WbT[(c4 * 4 + 3) * 72 + k] = (__bf16)wv.w;
    }
    // u = W@a1, v = W@a2 (exact f32 from global W)
    if (t < 64) {
        float s = 0.f;
#pragma unroll 8
        for (int f = 0; f < 64; f++) s = fmaf(W[t * 64 + f], a[f], s);
        uv[t] = s;
    } else if (t < 128) {
        int k = t - 64;
        float s = 0.f;
#pragma unroll 8
        for (int f = 0; f < 64; f++) s = fmaf(W[k * 64 + f], a[64 + f], s);
        uv[64 + k] = s;
    }
    __syncthreads();
    // x,y scalars: 4 threads per row, shfl reduce
    {
        int row = t >> 2, q = t & 3;
        const float* hp = &hT[row * 68 + q * 16];
        const float* up = &uv[q * 16];
        const float* vp = &uv[64 + q * 16];
        float sx = 0.f, sy = 0.f;
#pragma unroll
        for (int k2 = 0; k2 < 16; k2++) {
            float hv = hp[k2];
            sx = fmaf(hv, up[k2], sx);
            sy = fmaf(hv, vp[k2], sy);
        }
        sx += __shfl_xor(sx, 1); sx += __shfl_xor(sx, 2);
        sy += __shfl_xor(sy, 1); sy += __shfl_xor(sy, 2);
        if (q == 0) {
            int r = r0 + row;
            ys[r]   = T_SCALE * sy;
            xs_u[r] = __builtin_amdgcn_fmed3f(sx * INV_DXG + U_BIAS, 0.f, U_MAX);
            ys_u[r] = __builtin_amdgcn_fmed3f(sy * INV_DXG + U_BIAS, 0.f, U_MAX);
        }
    }
    // Wh via MFMA: wave w -> 16-row tile; K=64 (2 k-steps); 4 n-tiles
    int w = t >> 6, lane = t & 63;
    int il = lane & 15, kg = lane >> 4;
    f32x4 acc0 = {0.f,0.f,0.f,0.f}, acc1 = {0.f,0.f,0.f,0.f};
    f32x4 acc2 = {0.f,0.f,0.f,0.f}, acc3 = {0.f,0.f,0.f,0.f};
#pragma unroll
    for (int ks = 0; ks < 2; ks++) {
        const float* ap = &hT[(w * 16 + il) * 68 + ks * 32 + kg * 8];
        bf16x8 af;
#pragma unroll
        for (int e = 0; e < 8; e++) af[e] = (__bf16)ap[e];
        bf16x8 b0 = *(const bf16x8*)&WbT[(0 * 16 + il) * 72 + ks * 32 + kg * 8];
        bf16x8 b1 = *(const bf16x8*)&WbT[(1 * 16 + il) * 72 + ks * 32 + kg * 8];
        bf16x8 b2 = *(const bf16x8*)&WbT[(2 * 16 + il) * 72 + ks * 32 + kg * 8];
        bf16x8 b3 = *(const bf16x8*)&WbT[(3 * 16 + il) * 72 + ks * 32 + kg * 8];
        acc0 = __builtin_amdgcn_mfma_f32_16x16x32_bf16(af, b0, acc0, 0, 0, 0);
        acc1 = __builtin_amdgcn_mfma_f32_16x16x32_bf16(af, b1, acc1, 0, 0, 0);
        acc2 = __builtin_amdgcn_mfma_f32_16x16x32_bf16(af, b2, acc2, 0, 0, 0);
        acc3 = __builtin_amdgcn_mfma_f32_16x16x32_bf16(af, b3, acc3, 0, 0, 0);
    }
    // C-layout -> LDS bf16 (col = il + nt*16, row = w*16 + kg*4 + r)
#pragma unroll
    for (int r = 0; r < 4; r++) {
        __bf16* vrow = &vT[(w * 16 + kg * 4 + r) * 74 + il];
        vrow[0]  = (__bf16)acc0[r];
        vrow[16] = (__bf16)acc1[r];
        vrow[32] = (__bf16)acc2[r];
        vrow[48] = (__bf16)acc3[r];
    }
    __syncthreads();
    // Emit B-fragments: slot (ksl, nt, lane'): elem e = Wh[ksl*32+(lane'>>4)*8+e][nt*16+(lane'&15)]
#pragma unroll
    for (int s = 0; s < 2; s++) {
        int oi    = t + s * 256;
        int lane2 = oi & 63;
        int nt2   = (oi >> 6) & 3;
        int ksl   = oi >> 8;
        int rbase = ksl * 32 + ((lane2 >> 4) << 3);
        int col   = nt2 * 16 + (lane2 & 15);
        short8 o;
#pragma unroll
        for (int e = 0; e < 8; e++)
            o[e] = __builtin_bit_cast(short, vT[(rbase + e) * 74 + col]);
        int ks_g = ((blockIdx.x & 31) << 1) | ksl;
        vfrag[((b * 64 + ks_g) * 4 + nt2) * 64 + lane2] = __builtin_bit_cast(uint4, o);
    }
    if (blockIdx.x < 16) {
        int i = blockIdx.x * 256 + t;
        gtab[i] = gexact(T_LO + ((float)i + 0.5f) / T_SCALE);
    } else if (blockIdx.x < 20) {
        int i = (blockIdx.x - 16) * 256 + t;
        gs[i] = gexact(2.f * XG_LO + (float)i * DXG);
    }
}

// ---------------- Pass B: F via histogram convolution (R13-validated math).
// Block = (b, 64-m chunk); per-block LDS x-histogram (8x redundancy per batch,
// cheap at this scale) + 128-tap-per-thread conv + quad shfl reduce.
__global__ __launch_bounds__(256) void k_fconv(const float* __restrict__ xs_u,
                                               const float* __restrict__ gs,
                                               float* __restrict__ F) {
    __shared__ float gsb[GS_N];      // 4 KB
    __shared__ float hxb[MG];        // 2 KB
    int t  = threadIdx.x;
    int b  = blockIdx.x >> 3;
    int mc = blockIdx.x & 7;         // 8 m-chunks of 64
    ((float4*)gsb)[t] = ((const float4*)gs)[t];
    hxb[t] = 0.f;
    hxb[t + 256] = 0.f;
    __syncthreads();
    // x-histogram (linear split): 2048 rows, 8 per thread
#pragma unroll
    for (int i = 0; i < 8; i++) {
        float xu = xs_u[b * NN + i * 256 + t];
        int   k  = (int)xu;
        float fr = xu - (float)k;
        atomicAdd(&hxb[k],     1.f - fr);
        atomicAdd(&hxb[k + 1], fr);
    }
    __syncthreads();
    // conv: 4 threads per m (q = k-slice of 128); F[m] = sum_k hx[k]*gs[k+m]
    int ml = t >> 2, q = t & 3;
    int m  = mc * 64 + ml;
    float acc = 0.f;
#pragma unroll 8
    for (int kk = 0; kk < 128; kk++) {
        int k = q * 128 + kk;
        acc = fmaf(hxb[k], gsb[k + m], acc);
    }
    acc += __shfl_xor(acc, 1);
    acc += __shfl_xor(acc, 2);
    if (q == 0) F[b * MG + m] = acc;
}

// ---------------- Pass C: G[b][m][f] = sum_j (g(xm*+y_j)*dinv_j) * Wh[j][f]
// (MFMA, K=2048; 1/D folded into the A-fragment). 8-way K-split, 512 threads.
// [R18 verbatim]
__global__ __launch_bounds__(512) void k_gbuild(const float* __restrict__ ys,
                                                const float* __restrict__ ys_u,
                                                const float* __restrict__ F,
                                                const float* __restrict__ gtab,
                                                const uint4* __restrict__ vfrag,
                                                float* __restrict__ G) {
    __shared__ float stab[NT];       // 16 KB
    __shared__ float dinvb[NN];      // 8 KB
    __shared__ float red[7][16][65]; // 29 KB
    {
        const float4* src = (const float4*)gtab;
        float4*       dst = (float4*)stab;
#pragma unroll
        for (int k = 0; k < NT / 4 / 512; k++) dst[threadIdx.x + k * 512] = src[threadIdx.x + k * 512];
    }
    int b  = blockIdx.x >> 5;
    int ib = blockIdx.x & 31;
    // dinv prologue: 2048 lerp(F)+rcp, 4 per thread
    {
        const float* Fb = F + b * MG;
#pragma unroll
        for (int i = 0; i < 4; i++) {
            int j = threadIdx.x + i * 512;
            float u  = ys_u[b * NN + j];
            int   k  = (int)u;
            float fr = u - (float)k;
            float d  = fmaf(Fb[k + 1] - Fb[k], fr, Fb[k]);
            dinvb[j] = __builtin_amdgcn_rcpf(d);
        }
    }
    int kz = threadIdx.x >> 6, lane = threadIdx.x & 63;
    int il = lane & 15, kg = lane >> 4;
    int mbase = ib * 16;

    float xgb = (XG_LO + (float)(mbase + il) * DXG) * T_SCALE + Z_BIAS;
    const float* ysb = ys + b * NN;
    const uint4* vfb = vfrag + b * 16384 + lane;
    __syncthreads();

    f32x4 acc0 = {0.f,0.f,0.f,0.f}, acc1 = {0.f,0.f,0.f,0.f};
    f32x4 acc2 = {0.f,0.f,0.f,0.f}, acc3 = {0.f,0.f,0.f,0.f};

    for (int ks = kz * 8; ks < kz * 8 + 8; ks++) {
        const float* yp = ysb + ks * 32 + kg * 8;
        const float* dp = &dinvb[ks * 32 + kg * 8];
        float4 ya = *reinterpret_cast<const float4*>(yp);
        float4 yb = *reinterpret_cast<const float4*>(yp + 4);
        float wv[8];
        wv[0] = tlookup(stab, xgb + ya.x);
        wv[1] = tlookup(stab, xgb + ya.y);
        wv[2] = tlookup(stab, xgb + ya.z);
        wv[3] = tlookup(stab, xgb + ya.w);
        wv[4] = tlookup(stab, xgb + yb.x);
        wv[5] = tlookup(stab, xgb + yb.y);
        wv[6] = tlookup(stab, xgb + yb.z);
        wv[7] = tlookup(stab, xgb + yb.w);
        bf16x8 af;
#pragma unroll
        for (int e = 0; e < 8; e++) af[e] = (__bf16)(wv[e] * dp[e]);

        const uint4* vp = vfb + ks * 256;
        bf16x8 b0 = __builtin_bit_cast(bf16x8, vp[0]);
        bf16x8 b1 = __builtin_bit_cast(bf16x8, vp[64]);
        bf16x8 b2 = __builtin_bit_cast(bf16x8, vp[128]);
        bf16x8 b3 = __builtin_bit_cast(bf16x8, vp[192]);

        acc0 = __builtin_amdgcn_mfma_f32_16x16x32_bf16(af, b0, acc0, 0, 0, 0);
        acc1 = __builtin_amdgcn_mfma_f32_16x16x32_bf16(af, b1, acc1, 0, 0, 0);
        acc2 = __builtin_amdgcn_mfma_f32_16x16x32_bf16(af, b2, acc2, 0, 0, 0);
        acc3 = __builtin_amdgcn_mfma_f32_16x16x32_bf16(af, b3, acc3, 0, 0, 0);
    }

    if (kz > 0) {
#pragma unroll
        for (int r = 0; r < 4; r++) {
            float* rp = &red[kz - 1][kg * 4 + r][il];
            rp[0]  = acc0[r];
            rp[16] = acc1[r];
            rp[32] = acc2[r];
            rp[48] = acc3[r];
        }
    }
    __syncthreads();
    if (kz == 0) {
        int gbase = (b * MG + mbase + kg * 4) * 64 + il;
#pragma unroll
        for (int r = 0; r < 4; r++) {
            float s0 = acc0[r], s1 = acc1[r], s2 = acc2[r], s3 = acc3[r];
#pragma unroll
            for (int p = 0; p < 7; p++) {
                const float* rp = &red[p][kg * 4 + r][il];
                s0 += rp[0]; s1 += rp[16]; s2 += rp[32]; s3 += rp[48];
            }
            float* grow = G + gbase + r * 64;
            grow[0] = s0; grow[16] = s1; grow[32] = s2; grow[48] = s3;
        }
    }
}

// ---------------- Pass D: out[i][f] = ELU( lerp_x(G_b)(x_i)[f] )  [R18 verbatim]
__global__ __launch_bounds__(256) void k_apply(const float* __restrict__ xs_u,
                                               const float* __restrict__ G,
                                               float* __restrict__ out) {
    int w = threadIdx.x >> 6, f = threadIdx.x & 63;
    int r = blockIdx.x * 4 + w;
    int b = r >> 11;
    float u  = xs_u[r];
    int   k  = (int)u;
    float fr = u - (float)k;
    const float* Gb = G + (b * MG + k) * 64;
    float g0 = Gb[f];
    float g1 = Gb[64 + f];
    out[r * 64 + f] = elu(fmaf(g1 - g0, fr, g0));
}

extern "C" void kernel_launch(void* const* d_in, const int* in_sizes, int n_in,
                              void* d_out, int out_size, void* d_ws, size_t ws_size,
                              hipStream_t stream) {
    const float* h = (const float*)d_in[0];
    const float* W = (const float*)d_in[1];
    const float* a = (const float*)d_in[2];
    float* out = (float*)d_out;

    // workspace layout (floats), ~7 MB total
    float*  ys    = (float*)d_ws;                  // B*N (z-scaled y)
    float*  xs_u  = ys + NB * NN;                  // B*N (grid coords of x)
    float*  ys_u  = xs_u + NB * NN;                // B*N (grid coords of y)
    float*  F     = ys_u + NB * NN;                // B*MG = 8,192 f
    float*  G     = F + NB * MG;                   // B*MG*64 = 524,288 f
    uint4*  vfrag = (uint4*)(G + NB * MG * NF);    // B*N*64 bf16 = 4 MB
    float*  gtab  = (float*)(vfrag + NB * NN * NF / 8);  // 4096 f32
    float*  gs    = gtab + NT;                     // 1024 f32

    k_prep<<<dim3(NB * NN / 64), dim3(256), 0, stream>>>(h, W, a, vfrag, ys, xs_u, ys_u, gtab, gs);
    k_fconv<<<dim3(NB * 8), dim3(256), 0, stream>>>(xs_u, gs, F);
    k_gbuild<<<dim3(NB * (MG / 16)), dim3(512), 0, stream>>>(ys, ys_u, F, gtab, vfrag, G);
    k_apply<<<dim3(NB * NN / 4), dim3(256), 0, stream>>>(xs_u, G, out);
}

// Round 21
// 39.979 us; speedup vs baseline: 1.2641x; 1.0211x over previous
//
#include <hip/hip_runtime.h>
#include <hip/hip_bf16.h>
#include <math.h>

// Sizes fixed by the reference: B=16, N=2048, F_in=F_out=64.
#define NB 16
#define NN 2048
#define NF 64
#define LOG2E 1.44269504f

// g(t) nearest-neighbor table: t in [T_LO, T_HI], NT bins, value at bin midpoint.
#define NT 4096
#define T_LO (-40.0f)
#define T_HI (10.0f)
#define T_SCALE (NT / (T_HI - T_LO))         // 81.92 bins per unit t
#define Z_BIAS (-T_LO * T_SCALE)             // 3276.8
#define Z_MAX ((float)(NT - 1))

// F/G sampling grid (in t-units): 512 points over [-96, 96), step 0.375.
// gs[p] = g(2*XG_LO + p*DXG), p in [0,1024): composed grid for the F-convolution.
#define MG 512
#define XG_LO (-96.0f)
#define DXG 0.375f
#define INV_DXG (1.0f / DXG)                 // 2.666667
#define U_BIAS (-XG_LO * INV_DXG)            // 256.0
#define U_MAX 510.999f                       // clamp so k+1 <= 511
#define GS_N 1024

typedef __attribute__((ext_vector_type(8))) __bf16 bf16x8;
typedef __attribute__((ext_vector_type(8))) short  short8;
typedef __attribute__((ext_vector_type(4))) float  f32x4;

__device__ __forceinline__ float gexact(float t) {
    float v = t >= 0.f ? t : 0.2f * t;
    float s = 1.f / (1.f + expf(-v));
    return expf(s);
}

__device__ __forceinline__ float tlookup(const float* __restrict__ stab, float z) {
    float zc = __builtin_amdgcn_fmed3f(z, 0.f, Z_MAX);
    return stab[(int)zc];
}

__device__ __forceinline__ float elu(float v) {
    return v > 0.f ? v : (__builtin_amdgcn_exp2f(v * LOG2E) - 1.f);
}

// ---------------- Pass A: Wh via bf16 MFMA -> B-fragments; x,y scalars via
// associativity; PLUS this block's additive contribution to F (distributed
// histogram-convolution, R13-validated math; F zeroed by the memset node).
// Blocks 0..15 build gtab.
__global__ __launch_bounds__(256) void k_prep(const float* __restrict__ h,
                                              const float* __restrict__ W,
                                              const float* __restrict__ a,
                                              uint4* __restrict__ vfrag,
                                              float* __restrict__ ys,
                                              float* __restrict__ xs_u,
                                              float* __restrict__ ys_u,
                                              float* __restrict__ F,
                                              float* __restrict__ gtab) {
    __shared__ __attribute__((aligned(16))) float  hT[64 * 68];    // padded (+4 f32)
    __shared__ __attribute__((aligned(16))) __bf16 WbT[64 * 72];   // transposed, padded
    __shared__ __attribute__((aligned(16))) __bf16 vT[64 * 74];    // Wh bf16, stride-74
    __shared__ float uv[128];                                      // u[0..64), v[64..128)
    __shared__ float gsb[GS_N];                                    // 4 KB, built locally
    __shared__ int   kuA[64];
    __shared__ float frA[64];
    int t  = threadIdx.x;
    int r0 = blockIdx.x * 64;
    int b  = blockIdx.x >> 5;
    // local gs build (4 gexact per thread)
#pragma unroll
    for (int i = t; i < GS_N; i += 256)
        gsb[i] = gexact(2.f * XG_LO + (float)i * DXG);
    const float4* hsrc = (const float4*)(h + r0 * 64);
#pragma unroll
    for (int i = 0; i < 4; i++) {
        int flat = t + i * 256;            // float4 index in 64x16
        int row = flat >> 4, c4 = flat & 15;
        float4 hv = hsrc[flat];
        float* dst = &hT[row * 68 + c4 * 4];
        dst[0] = hv.x; dst[1] = hv.y; dst[2] = hv.z; dst[3] = hv.w;
    }
#pragma unroll
    for (int i = 0; i < 4; i++) {
        int flat = t + i * 256;
        int k = flat >> 4, c4 = flat & 15;
        float4 wv = ((const float4*)W)[flat];
        WbT[(c4 * 4 + 0) * 72 + k] = (__bf16)wv.x;
        WbT[(c4 * 4 + 1) * 72 + k] = (__bf16)wv.y;
        WbT[(c4 * 4 + 2) * 72 + k] = (__bf16)wv.z;
        WbT[(c4 * 4 + 3) * 72 + k] = (__bf16)wv.w;
    }
    // u = W@a1, v = W@a2 (exact f32 from global W)
    if (t < 64) {
        float s = 0.f;
#pragma unroll 8
        for (int f = 0; f < 64; f++) s = fmaf(W[t * 64 + f], a[f], s);
        uv[t] = s;
    } else if (t < 128) {
        int k = t - 64;
        float s = 0.f;
#pragma unroll 8
        for (int f = 0; f < 64; f++) s = fmaf(W[k * 64 + f], a[64 + f], s);
        uv[64 + k] = s;
    }
    __syncthreads();
    // x,y scalars: 4 threads per row, shfl reduce
    {
        int row = t >> 2, q = t & 3;
        const float* hp = &hT[row * 68 + q * 16];
        const float* up = &uv[q * 16];
        const float* vp = &uv[64 + q * 16];
        float sx = 0.f, sy = 0.f;
#pragma unroll
        for (int k2 = 0; k2 < 16; k2++) {
            float hv = hp[k2];
            sx = fmaf(hv, up[k2], sx);
            sy = fmaf(hv, vp[k2], sy);
        }
        sx += __shfl_xor(sx, 1); sx += __shfl_xor(sx, 2);
        sy += __shfl_xor(sy, 1); sy += __shfl_xor(sy, 2);
        if (q == 0) {
            int r = r0 + row;
            float xu = __builtin_amdgcn_fmed3f(sx * INV_DXG + U_BIAS, 0.f, U_MAX);
            ys[r]   = T_SCALE * sy;
            xs_u[r] = xu;
            ys_u[r] = __builtin_amdgcn_fmed3f(sy * INV_DXG + U_BIAS, 0.f, U_MAX);
            int ku  = (int)xu;
            kuA[row] = ku;
            frA[row] = xu - (float)ku;
        }
    }
    // Wh via MFMA: wave w -> 16-row tile; K=64 (2 k-steps); 4 n-tiles
    int w = t >> 6, lane = t & 63;
    int il = lane & 15, kg = lane >> 4;
    f32x4 acc0 = {0.f,0.f,0.f,0.f}, acc1 = {0.f,0.f,0.f,0.f};
    f32x4 acc2 = {0.f,0.f,0.f,0.f}, acc3 = {0.f,0.f,0.f,0.f};
#pragma unroll
    for (int ks = 0; ks < 2; ks++) {
        const float* ap = &hT[(w * 16 + il) * 68 + ks * 32 + kg * 8];
        bf16x8 af;
#pragma unroll
        for (int e = 0; e < 8; e++) af[e] = (__bf16)ap[e];
        bf16x8 b0 = *(const bf16x8*)&WbT[(0 * 16 + il) * 72 + ks * 32 + kg * 8];
        bf16x8 b1 = *(const bf16x8*)&WbT[(1 * 16 + il) * 72 + ks * 32 + kg * 8];
        bf16x8 b2 = *(const bf16x8*)&WbT[(2 * 16 + il) * 72 + ks * 32 + kg * 8];
        bf16x8 b3 = *(const bf16x8*)&WbT[(3 * 16 + il) * 72 + ks * 32 + kg * 8];
        acc0 = __builtin_amdgcn_mfma_f32_16x16x32_bf16(af, b0, acc0, 0, 0, 0);
        acc1 = __builtin_amdgcn_mfma_f32_16x16x32_bf16(af, b1, acc1, 0, 0, 0);
        acc2 = __builtin_amdgcn_mfma_f32_16x16x32_bf16(af, b2, acc2, 0, 0, 0);
        acc3 = __builtin_amdgcn_mfma_f32_16x16x32_bf16(af, b3, acc3, 0, 0, 0);
    }
    // C-layout -> LDS bf16 (col = il + nt*16, row = w*16 + kg*4 + r)
#pragma unroll
    for (int r = 0; r < 4; r++) {
        __bf16* vrow = &vT[(w * 16 + kg * 4 + r) * 74 + il];
        vrow[0]  = (__bf16)acc0[r];
        vrow[16] = (__bf16)acc1[r];
        vrow[32] = (__bf16)acc2[r];
        vrow[48] = (__bf16)acc3[r];
    }
    __syncthreads();   // covers vT, kuA/frA, gsb
    // Emit B-fragments: slot (ksl, nt, lane'): elem e = Wh[ksl*32+(lane'>>4)*8+e][nt*16+(lane'&15)]
#pragma unroll
    for (int s = 0; s < 2; s++) {
        int oi    = t + s * 256;
        int lane2 = oi & 63;
        int nt2   = (oi >> 6) & 3;
        int ksl   = oi >> 8;
        int rbase = ksl * 32 + ((lane2 >> 4) << 3);
        int col   = nt2 * 16 + (lane2 & 15);
        short8 o;
#pragma unroll
        for (int e = 0; e < 8; e++)
            o[e] = __builtin_bit_cast(short, vT[(rbase + e) * 74 + col]);
        int ks_g = ((blockIdx.x & 31) << 1) | ksl;
        vfrag[((b * 64 + ks_g) * 4 + nt2) * 64 + lane2] = __builtin_bit_cast(uint4, o);
    }
    // Distributed F contribution: thread t owns m = t and m = t+256.
    // gsb[ku + t] is stride-1 across lanes -> conflict-free; ku/fr broadcast.
    {
        float a0 = 0.f, a1 = 0.f;
#pragma unroll 8
        for (int r = 0; r < 64; r++) {
            int   ku = kuA[r];
            float fr = frA[r];
            float w0 = 1.f - fr;
            const float* g0 = &gsb[ku + t];
            const float* g1 = &gsb[ku + t + 256];
            a0 = fmaf(w0, g0[0], a0); a0 = fmaf(fr, g0[1], a0);
            a1 = fmaf(w0, g1[0], a1); a1 = fmaf(fr, g1[1], a1);
        }
        atomicAdd(&F[b * MG + t], a0);
        atomicAdd(&F[b * MG + t + 256], a1);
    }
    if (blockIdx.x < 16) {
        int i = blockIdx.x * 256 + t;
        gtab[i] = gexact(T_LO + ((float)i + 0.5f) / T_SCALE);
    }
}

// ---------------- Pass B: G[b][m][f] = sum_j (g(xm*+y_j)*dinv_j) * Wh[j][f]
// (MFMA, K=2048; 1/D folded into the A-fragment). 8-way K-split, 512 threads.
// [R18 verbatim]
__global__ __launch_bounds__(512) void k_gbuild(const float* __restrict__ ys,
                                                const float* __restrict__ ys_u,
                                                const float* __restrict__ F,
                                                const float* __restrict__ gtab,
                                                const uint4* __restrict__ vfrag,
                                                float* __restrict__ G) {
    __shared__ float stab[NT];       // 16 KB
    __shared__ float dinvb[NN];      // 8 KB
    __shared__ float red[7][16][65]; // 29 KB
    {
        const float4* src = (const float4*)gtab;
        float4*       dst = (float4*)stab;
#pragma unroll
        for (int k = 0; k < NT / 4 / 512; k++) dst[threadIdx.x + k * 512] = src[threadIdx.x + k * 512];
    }
    int b  = blockIdx.x >> 5;
    int ib = blockIdx.x & 31;
    // dinv prologue: 2048 lerp(F)+rcp, 4 per thread
    {
        const float* Fb = F + b * MG;
#pragma unroll
        for (int i = 0; i < 4; i++) {
            int j = threadIdx.x + i * 512;
            float u  = ys_u[b * NN + j];
            int   k  = (int)u;
            float fr = u - (float)k;
            float d  = fmaf(Fb[k + 1] - Fb[k], fr, Fb[k]);
            dinvb[j] = __builtin_amdgcn_rcpf(d);
        }
    }
    int kz = threadIdx.x >> 6, lane = threadIdx.x & 63;
    int il = lane & 15, kg = lane >> 4;
    int mbase = ib * 16;

    float xgb = (XG_LO + (float)(mbase + il) * DXG) * T_SCALE + Z_BIAS;
    const float* ysb = ys + b * NN;
    const uint4* vfb = vfrag + b * 16384 + lane;
    __syncthreads();

    f32x4 acc0 = {0.f,0.f,0.f,0.f}, acc1 = {0.f,0.f,0.f,0.f};
    f32x4 acc2 = {0.f,0.f,0.f,0.f}, acc3 = {0.f,0.f,0.f,0.f};

    for (int ks = kz * 8; ks < kz * 8 + 8; ks++) {
        const float* yp = ysb + ks * 32 + kg * 8;
        const float* dp = &dinvb[ks * 32 + kg * 8];
        float4 ya = *reinterpret_cast<const float4*>(yp);
        float4 yb = *reinterpret_cast<const float4*>(yp + 4);
        float wv[8];
        wv[0] = tlookup(stab, xgb + ya.x);
        wv[1] = tlookup(stab, xgb + ya.y);
        wv[2] = tlookup(stab, xgb + ya.z);
        wv[3] = tlookup(stab, xgb + ya.w);
        wv[4] = tlookup(stab, xgb + yb.x);
        wv[5] = tlookup(stab, xgb + yb.y);
        wv[6] = tlookup(stab, xgb + yb.z);
        wv[7] = tlookup(stab, xgb + yb.w);
        bf16x8 af;
#pragma unroll
        for (int e = 0; e < 8; e++) af[e] = (__bf16)(wv[e] * dp[e]);

        const uint4* vp = vfb + ks * 256;
        bf16x8 b0 = __builtin_bit_cast(bf16x8, vp[0]);
        bf16x8 b1 = __builtin_bit_cast(bf16x8, vp[64]);
        bf16x8 b2 = __builtin_bit_cast(bf16x8, vp[128]);
        bf16x8 b3 = __builtin_bit_cast(bf16x8, vp[192]);

        acc0 = __builtin_amdgcn_mfma_f32_16x16x32_bf16(af, b0, acc0, 0, 0, 0);
        acc1 = __builtin_amdgcn_mfma_f32_16x16x32_bf16(af, b1, acc1, 0, 0, 0);
        acc2 = __builtin_amdgcn_mfma_f32_16x16x32_bf16(af, b2, acc2, 0, 0, 0);
        acc3 = __builtin_amdgcn_mfma_f32_16x16x32_bf16(af, b3, acc3, 0, 0, 0);
    }

    if (kz > 0) {
#pragma unroll
        for (int r = 0; r < 4; r++) {
            float* rp = &red[kz - 1][kg * 4 + r][il];
            rp[0]  = acc0[r];
            rp[16] = acc1[r];
            rp[32] = acc2[r];
            rp[48] = acc3[r];
        }
    }
    __syncthreads();
    if (kz == 0) {
        int gbase = (b * MG + mbase + kg * 4) * 64 + il;
#pragma unroll
        for (int r = 0; r < 4; r++) {
            float s0 = acc0[r], s1 = acc1[r], s2 = acc2[r], s3 = acc3[r];
#pragma unroll
            for (int p = 0; p < 7; p++) {
                const float* rp = &red[p][kg * 4 + r][il];
                s0 += rp[0]; s1 += rp[16]; s2 += rp[32]; s3 += rp[48];
            }
            float* grow = G + gbase + r * 64;
            grow[0] = s0; grow[16] = s1; grow[32] = s2; grow[48] = s3;
        }
    }
}

// ---------------- Pass C: out[i][f] = ELU( lerp_x(G_b)(x_i)[f] )  [R18 verbatim]
__global__ __launch_bounds__(256) void k_apply(const float* __restrict__ xs_u,
                                               const float* __restrict__ G,
                                               float* __restrict__ out) {
    int w = threadIdx.x >> 6, f = threadIdx.x & 63;
    int r = blockIdx.x * 4 + w;
    int b = r >> 11;
    float u  = xs_u[r];
    int   k  = (int)u;
    float fr = u - (float)k;
    const float* Gb = G + (b * MG + k) * 64;
    float g0 = Gb[f];
    float g1 = Gb[64 + f];
    out[r * 64 + f] = elu(fmaf(g1 - g0, fr, g0));
}

extern "C" void kernel_launch(void* const* d_in, const int* in_sizes, int n_in,
                              void* d_out, int out_size, void* d_ws, size_t ws_size,
                              hipStream_t stream) {
    const float* h = (const float*)d_in[0];
    const float* W = (const float*)d_in[1];
    const float* a = (const float*)d_in[2];
    float* out = (float*)d_out;

    // workspace layout (floats), ~7 MB total
    float*  ys    = (float*)d_ws;                  // B*N (z-scaled y)
    float*  xs_u  = ys + NB * NN;                  // B*N (grid coords of x)
    float*  ys_u  = xs_u + NB * NN;                // B*N (grid coords of y)
    float*  F     = ys_u + NB * NN;                // B*MG = 8,192 f (atomic-accumulated)
    float*  G     = F + NB * MG;                   // B*MG*64 = 524,288 f
    uint4*  vfrag = (uint4*)(G + NB * MG * NF);    // B*N*64 bf16 = 4 MB
    float*  gtab  = (float*)(vfrag + NB * NN * NF / 8);  // 4096 f32

    hipMemsetAsync(F, 0, NB * MG * sizeof(float), stream);
    k_prep<<<dim3(NB * NN / 64), dim3(256), 0, stream>>>(h, W, a, vfrag, ys, xs_u, ys_u, F, gtab);
    k_gbuild<<<dim3(NB * (MG / 16)), dim3(512), 0, stream>>>(ys, ys_u, F, gtab, vfrag, G);
    k_apply<<<dim3(NB * NN / 4), dim3(256), 0, stream>>>(xs_u, G, out);
}

// Round 22
// 35.104 us; speedup vs baseline: 1.4396x; 1.1389x over previous
//
#include <hip/hip_runtime.h>
#include <hip/hip_bf16.h>
#include <math.h>

// Sizes fixed by the reference: B=16, N=2048, F_in=F_out=64.
#define NB 16
#define NN 2048
#define NF 64
#define LOG2E 1.44269504f

// g(t) nearest-neighbor table: t in [T_LO, T_HI], NT bins, value at bin midpoint.
#define NT 4096
#define T_LO (-40.0f)
#define T_HI (10.0f)
#define T_SCALE (NT / (T_HI - T_LO))         // 81.92 bins per unit t
#define Z_BIAS (-T_LO * T_SCALE)             // 3276.8
#define Z_MAX ((float)(NT - 1))

// F sampling grid: 512 points over [-96, 96), step 0.375 (division-sensitive).
#define MG 512
#define XG_LO (-96.0f)
#define DXG 0.375f
#define INV_DXG (1.0f / DXG)                 // 2.666667
#define U_BIAS (-XG_LO * INV_DXG)            // 256.0
#define U_MAX 510.999f                       // clamp so k+1 <= 511

// G sampling grid: 256 points over [-96, 96), step 0.75 (double-smoothed output).
#define MGG 256
#define DXGG 0.75f
#define UG_MAX 254.999f                      // clamp so k+1 <= 255

typedef __attribute__((ext_vector_type(8))) __bf16 bf16x8;
typedef __attribute__((ext_vector_type(8))) short  short8;
typedef __attribute__((ext_vector_type(4))) float  f32x4;

__device__ __forceinline__ float gexact(float t) {
    float v = t >= 0.f ? t : 0.2f * t;
    float s = 1.f / (1.f + expf(-v));
    return expf(s);
}

__device__ __forceinline__ float tlookup(const float* __restrict__ stab, float z) {
    float zc = __builtin_amdgcn_fmed3f(z, 0.f, Z_MAX);
    return stab[(int)zc];
}

__device__ __forceinline__ float elu(float v) {
    return v > 0.f ? v : (__builtin_amdgcn_exp2f(v * LOG2E) - 1.f);
}

// ---------------- Pass A: Wh via bf16 MFMA, emitted directly as MFMA B-fragments;
// x,y scalars via associativity (h.(W@a1)). Blocks 0..15 build gtab.  [R18 verbatim]
__global__ __launch_bounds__(256) void k_prep(const float* __restrict__ h,
                                              const float* __restrict__ W,
                                              const float* __restrict__ a,
                                              uint4* __restrict__ vfrag,
                                              float* __restrict__ xs,
                                              float* __restrict__ ys,
                                              float* __restrict__ xs_u,
                                              float* __restrict__ ys_u,
                                              float* __restrict__ gtab) {
    __shared__ __attribute__((aligned(16))) float  hT[64 * 68];    // padded (+4 f32)
    __shared__ __attribute__((aligned(16))) __bf16 WbT[64 * 72];   // transposed, padded
    __shared__ __attribute__((aligned(16))) __bf16 vT[64 * 74];    // Wh bf16, stride-74
    __shared__ float uv[128];                                      // u[0..64), v[64..128)
    int t  = threadIdx.x;
    int r0 = blockIdx.x * 64;
    int b  = blockIdx.x >> 5;
    const float4* hsrc = (const float4*)(h + r0 * 64);
#pragma unroll
    for (int i = 0; i < 4; i++) {
        int flat = t + i * 256;            // float4 index in 64x16
        int row = flat >> 4, c4 = flat & 15;
        float4 hv = hsrc[flat];
        float* dst = &hT[row * 68 + c4 * 4];
        dst[0] = hv.x; dst[1] = hv.y; dst[2] = hv.z; dst[3] = hv.w;
    }
#pragma unroll
    for (int i = 0; i < 4; i++) {
        int flat = t + i * 256;
        int k = flat >> 4, c4 = flat & 15;
        float4 wv = ((const float4*)W)[flat];
        WbT[(c4 * 4 + 0) * 72 + k] = (__bf16)wv.x;
        WbT[(c4 * 4 + 1) * 72 + k] = (__bf16)wv.y;
        WbT[(c4 * 4 + 2) * 72 + k] = (__bf16)wv.z;
        WbT[(c4 * 4 + 3) * 72 + k] = (__bf16)wv.w;
    }
    // u = W@a1, v = W@a2 (exact f32 from global W)
    if (t < 64) {
        float s = 0.f;
#pragma unroll 8
        for (int f = 0; f < 64; f++) s = fmaf(W[t * 64 + f], a[f], s);
        uv[t] = s;
    } else if (t < 128) {
        int k = t - 64;
        float s = 0.f;
#pragma unroll 8
        for (int f = 0; f < 64; f++) s = fmaf(W[k * 64 + f], a[64 + f], s);
        uv[64 + k] = s;
    }
    __syncthreads();
    // x,y scalars: 4 threads per row, shfl reduce
    {
        int row = t >> 2, q = t & 3;
        const float* hp = &hT[row * 68 + q * 16];
        const float* up = &uv[q * 16];
        const float* vp = &uv[64 + q * 16];
        float sx = 0.f, sy = 0.f;
#pragma unroll
        for (int k2 = 0; k2 < 16; k2++) {
            float hv = hp[k2];
            sx = fmaf(hv, up[k2], sx);
            sy = fmaf(hv, vp[k2], sy);
        }
        sx += __shfl_xor(sx, 1); sx += __shfl_xor(sx, 2);
        sy += __shfl_xor(sy, 1); sy += __shfl_xor(sy, 2);
        if (q == 0) {
            int r = r0 + row;
            xs[r]   = T_SCALE * sx;
            ys[r]   = T_SCALE * sy;
            xs_u[r] = __builtin_amdgcn_fmed3f(sx * INV_DXG + U_BIAS, 0.f, U_MAX);
            ys_u[r] = __builtin_amdgcn_fmed3f(sy * INV_DXG + U_BIAS, 0.f, U_MAX);
        }
    }
    // Wh via MFMA: wave w -> 16-row tile; K=64 (2 k-steps); 4 n-tiles
    int w = t >> 6, lane = t & 63;
    int il = lane & 15, kg = lane >> 4;
    f32x4 acc0 = {0.f,0.f,0.f,0.f}, acc1 = {0.f,0.f,0.f,0.f};
    f32x4 acc2 = {0.f,0.f,0.f,0.f}, acc3 = {0.f,0.f,0.f,0.f};
#pragma unroll
    for (int ks = 0; ks < 2; ks++) {
        const float* ap = &hT[(w * 16 + il) * 68 + ks * 32 + kg * 8];
        bf16x8 af;
#pragma unroll
        for (int e = 0; e < 8; e++) af[e] = (__bf16)ap[e];
        bf16x8 b0 = *(const bf16x8*)&WbT[(0 * 16 + il) * 72 + ks * 32 + kg * 8];
        bf16x8 b1 = *(const bf16x8*)&WbT[(1 * 16 + il) * 72 + ks * 32 + kg * 8];
        bf16x8 b2 = *(const bf16x8*)&WbT[(2 * 16 + il) * 72 + ks * 32 + kg * 8];
        bf16x8 b3 = *(const bf16x8*)&WbT[(3 * 16 + il) * 72 + ks * 32 + kg * 8];
        acc0 = __builtin_amdgcn_mfma_f32_16x16x32_bf16(af, b0, acc0, 0, 0, 0);
        acc1 = __builtin_amdgcn_mfma_f32_16x16x32_bf16(af, b1, acc1, 0, 0, 0);
        acc2 = __builtin_amdgcn_mfma_f32_16x16x32_bf16(af, b2, acc2, 0, 0, 0);
        acc3 = __builtin_amdgcn_mfma_f32_16x16x32_bf16(af, b3, acc3, 0, 0, 0);
    }
    // C-layout -> LDS bf16 (col = il + nt*16, row = w*16 + kg*4 + r)
#pragma unroll
    for (int r = 0; r < 4; r++) {
        __bf16* vrow = &vT[(w * 16 + kg * 4 + r) * 74 + il];
        vrow[0]  = (__bf16)acc0[r];
        vrow[16] = (__bf16)acc1[r];
        vrow[32] = (__bf16)acc2[r];
        vrow[48] = (__bf16)acc3[r];
    }
    __syncthreads();
    // Emit B-fragments: slot (ksl, nt, lane'): elem e = Wh[ksl*32+(lane'>>4)*8+e][nt*16+(lane'&15)]
#pragma unroll
    for (int s = 0; s < 2; s++) {
        int oi    = t + s * 256;
        int lane2 = oi & 63;
        int nt2   = (oi >> 6) & 3;
        int ksl   = oi >> 8;
        int rbase = ksl * 32 + ((lane2 >> 4) << 3);
        int col   = nt2 * 16 + (lane2 & 15);
        short8 o;
#pragma unroll
        for (int e = 0; e < 8; e++)
            o[e] = __builtin_bit_cast(short, vT[(rbase + e) * 74 + col]);
        int ks_g = ((blockIdx.x & 31) << 1) | ksl;
        vfrag[((b * 64 + ks_g) * 4 + nt2) * 64 + lane2] = __builtin_bit_cast(uint4, o);
    }
    if (blockIdx.x < 16) {
        int i = blockIdx.x * 256 + t;
        gtab[i] = gexact(T_LO + ((float)i + 0.5f) / T_SCALE);
    }
}

// ---------------- Pass B: F[b][m] = sum_i g(x_i + ym*)  [R18 verbatim, MG=512]
__global__ __launch_bounds__(256) void k_fbuild(const float* __restrict__ xs,
                                                const float* __restrict__ gtab,
                                                float* __restrict__ F) {
    __shared__ float stab[NT];
    __shared__ float xsb[NN];
    int tid = threadIdx.x;
    {
        const float4* src = (const float4*)gtab;
        float4*       dst = (float4*)stab;
#pragma unroll
        for (int k = 0; k < NT / 4 / 256; k++) dst[tid + k * 256] = src[tid + k * 256];
    }
    int mg = blockIdx.x & 127;
    int b  = blockIdx.x >> 7;
    {
        const float4* src = (const float4*)(xs + b * NN);
        float4*       dst = (float4*)xsb;
#pragma unroll
        for (int k = 0; k < NN / 4 / 256; k++) dst[tid + k * 256] = src[tid + k * 256];
    }
    __syncthreads();
    int w = tid >> 6, lane = tid & 63;
    int m = mg * 4 + w;
    float ymb = (XG_LO + (float)m * DXG) * T_SCALE + Z_BIAS;
    float acc = 0.f;
#pragma unroll 8
    for (int i8 = 0; i8 < NN / 64; i8++)
        acc += tlookup(stab, xsb[i8 * 64 + lane] + ymb);
#pragma unroll
    for (int s = 32; s; s >>= 1) acc += __shfl_xor(acc, s, 64);
    if (lane == 0) F[b * MG + m] = acc;
}

// ---------------- Pass C: G[b][m][f] = sum_j (g(xm*+y_j)*dinv_j) * Wh[j][f]
// (MFMA, K=2048; 1/D on the A-side). G-grid = MGG=256 (step 0.75): gbuild
// halves to 256 blocks (1/CU). 8-way K-split, 512 threads.  [R18 structure]
__global__ __launch_bounds__(512) void k_gbuild(const float* __restrict__ ys,
                                                const float* __restrict__ ys_u,
                                                const float* __restrict__ F,
                                                const float* __restrict__ gtab,
                                                const uint4* __restrict__ vfrag,
                                                float* __restrict__ G) {
    __shared__ float stab[NT];       // 16 KB
    __shared__ float dinvb[NN];      // 8 KB
    __shared__ float red[7][16][65]; // 29 KB
    {
        const float4* src = (const float4*)gtab;
        float4*       dst = (float4*)stab;
#pragma unroll
        for (int k = 0; k < NT / 4 / 512; k++) dst[threadIdx.x + k * 512] = src[threadIdx.x + k * 512];
    }
    int b  = blockIdx.x >> 4;          // batch
    int ib = blockIdx.x & 15;          // 16 m-blocks of 16 sample rows (MGG=256)
    // dinv prologue: 2048 lerp(F)+rcp, 4 per thread (F-grid, MG=512)
    {
        const float* Fb = F + b * MG;
#pragma unroll
        for (int i = 0; i < 4; i++) {
            int j = threadIdx.x + i * 512;
            float u  = ys_u[b * NN + j];
            int   k  = (int)u;
            float fr = u - (float)k;
            float d  = fmaf(Fb[k + 1] - Fb[k], fr, Fb[k]);
            dinvb[j] = __builtin_amdgcn_rcpf(d);
        }
    }
    int kz = threadIdx.x >> 6, lane = threadIdx.x & 63;
    int il = lane & 15, kg = lane >> 4;
    int mbase = ib * 16;

    float xgb = (XG_LO + (float)(mbase + il) * DXGG) * T_SCALE + Z_BIAS;
    const float* ysb = ys + b * NN;
    const uint4* vfb = vfrag + b * 16384 + lane;
    __syncthreads();

    f32x4 acc0 = {0.f,0.f,0.f,0.f}, acc1 = {0.f,0.f,0.f,0.f};
    f32x4 acc2 = {0.f,0.f,0.f,0.f}, acc3 = {0.f,0.f,0.f,0.f};

    for (int ks = kz * 8; ks < kz * 8 + 8; ks++) {
        const float* yp = ysb + ks * 32 + kg * 8;
        const float* dp = &dinvb[ks * 32 + kg * 8];
        float4 ya = *reinterpret_cast<const float4*>(yp);
        float4 yb = *reinterpret_cast<const float4*>(yp + 4);
        float wv[8];
        wv[0] = tlookup(stab, xgb + ya.x);
        wv[1] = tlookup(stab, xgb + ya.y);
        wv[2] = tlookup(stab, xgb + ya.z);
        wv[3] = tlookup(stab, xgb + ya.w);
        wv[4] = tlookup(stab, xgb + yb.x);
        wv[5] = tlookup(stab, xgb + yb.y);
        wv[6] = tlookup(stab, xgb + yb.z);
        wv[7] = tlookup(stab, xgb + yb.w);
        bf16x8 af;
#pragma unroll
        for (int e = 0; e < 8; e++) af[e] = (__bf16)(wv[e] * dp[e]);

        const uint4* vp = vfb + ks * 256;
        bf16x8 b0 = __builtin_bit_cast(bf16x8, vp[0]);
        bf16x8 b1 = __builtin_bit_cast(bf16x8, vp[64]);
        bf16x8 b2 = __builtin_bit_cast(bf16x8, vp[128]);
        bf16x8 b3 = __builtin_bit_cast(bf16x8, vp[192]);

        acc0 = __builtin_amdgcn_mfma_f32_16x16x32_bf16(af, b0, acc0, 0, 0, 0);
        acc1 = __builtin_amdgcn_mfma_f32_16x16x32_bf16(af, b1, acc1, 0, 0, 0);
        acc2 = __builtin_amdgcn_mfma_f32_16x16x32_bf16(af, b2, acc2, 0, 0, 0);
        acc3 = __builtin_amdgcn_mfma_f32_16x16x32_bf16(af, b3, acc3, 0, 0, 0);
    }

    if (kz > 0) {
#pragma unroll
        for (int r = 0; r < 4; r++) {
            float* rp = &red[kz - 1][kg * 4 + r][il];
            rp[0]  = acc0[r];
            rp[16] = acc1[r];
            rp[32] = acc2[r];
            rp[48] = acc3[r];
        }
    }
    __syncthreads();
    if (kz == 0) {
        int gbase = (b * MGG + mbase + kg * 4) * 64 + il;
#pragma unroll
        for (int r = 0; r < 4; r++) {
            float s0 = acc0[r], s1 = acc1[r], s2 = acc2[r], s3 = acc3[r];
#pragma unroll
            for (int p = 0; p < 7; p++) {
                const float* rp = &red[p][kg * 4 + r][il];
                s0 += rp[0]; s1 += rp[16]; s2 += rp[32]; s3 += rp[48];
            }
            float* grow = G + gbase + r * 64;
            grow[0] = s0; grow[16] = s1; grow[32] = s2; grow[48] = s3;
        }
    }
}

// ---------------- Pass D: out[i][f] = ELU( lerp(G_b)(x_i)[f] ) on the MGG grid.
// u_g = xs_u/2 (F-grid coord -> G-grid coord, both anchored at XG_LO).
__global__ __launch_bounds__(256) void k_apply(const float* __restrict__ xs_u,
                                               const float* __restrict__ G,
                                               float* __restrict__ out) {
    int w = threadIdx.x >> 6, f = threadIdx.x & 63;
    int r = blockIdx.x * 4 + w;
    int b = r >> 11;
    float u  = fminf(xs_u[r] * 0.5f, UG_MAX);    // xs_u >= 0 already
    int   k  = (int)u;
    float fr = u - (float)k;
    const float* Gb = G + (b * MGG + k) * 64;
    float g0 = Gb[f];
    float g1 = Gb[64 + f];
    out[r * 64 + f] = elu(fmaf(g1 - g0, fr, g0));
}

extern "C" void kernel_launch(void* const* d_in, const int* in_sizes, int n_in,
                              void* d_out, int out_size, void* d_ws, size_t ws_size,
                              hipStream_t stream) {
    const float* h = (const float*)d_in[0];
    const float* W = (const float*)d_in[1];
    const float* a = (const float*)d_in[2];
    float* out = (float*)d_out;

    // workspace layout (floats), ~6 MB total
    float*  xs    = (float*)d_ws;                  // B*N (z-scaled x)
    float*  ys    = xs + NB * NN;                  // B*N (z-scaled y)
    float*  xs_u  = ys + NB * NN;                  // B*N (F-grid coords of x)
    float*  ys_u  = xs_u + NB * NN;                // B*N (F-grid coords of y)
    float*  F     = ys_u + NB * NN;                // B*MG = 8,192 f
    float*  G     = F + NB * MG;                   // B*MGG*64 = 262,144 f
    uint4*  vfrag = (uint4*)(G + NB * MGG * NF);   // B*N*64 bf16 = 4 MB
    float*  gtab  = (float*)(vfrag + NB * NN * NF / 8);  // 4096 f32

    k_prep<<<dim3(NB * NN / 64), dim3(256), 0, stream>>>(h, W, a, vfrag, xs, ys, xs_u, ys_u, gtab);
    k_fbuild<<<dim3(NB * (MG / 4)), dim3(256), 0, stream>>>(xs, gtab, F);
    k_gbuild<<<dim3(NB * (MGG / 16)), dim3(512), 0, stream>>>(ys, ys_u, F, gtab, vfrag, G);
    k_apply<<<dim3(NB * NN / 4), dim3(256), 0, stream>>>(xs_u, G, out);
}